// Round 4
// baseline (179.410 us; speedup 1.0000x reference)
//
#include <hip/hip_runtime.h>
#include <hip/hip_bf16.h>

#define NB   32
#define SQL  2048
#define DH   128
#define QBLK 128
#define KBLK 64

typedef __attribute__((ext_vector_type(4)))  float f32x4;
typedef __attribute__((ext_vector_type(16))) float f32x16;
typedef __attribute__((ext_vector_type(8)))  short s16x8;
typedef __attribute__((ext_vector_type(4)))  unsigned int u32x4;

__device__ __forceinline__ unsigned int cvtpk_bf16(float lo, float hi) {
  unsigned int r;
  asm("v_cvt_pk_bf16_f32 %0, %1, %2" : "=v"(r) : "v"(lo), "v"(hi));
  return r;
}
// x.hi32 = y.lo32 ; y.lo32 = x.hi32_old  (x keeps lo, y keeps hi)
#define PLSWAP(x, y) asm volatile("v_permlane32_swap_b32 %0, %1" : "+v"(x), "+v"(y))

__device__ __forceinline__ unsigned int pk2(float lo, float hi) {
  unsigned short a = __builtin_bit_cast(unsigned short, __float2bfloat16(lo));
  unsigned short b = __builtin_bit_cast(unsigned short, __float2bfloat16(hi));
  return (unsigned int)a | ((unsigned int)b << 16);
}

__global__ __launch_bounds__(256, 2)
void attn_fwd(const float* __restrict__ Qg, const float* __restrict__ Kg,
              const float* __restrict__ Vg, float* __restrict__ Og) {
  // K dbuf: 2 x [64][128] bf16 (256B rows, XOR-swizzled) at 0 / 16384
  // Vt dbuf: 2 x [128][64] bf16 (128B rows, XOR-swizzled) at 32768 / 49152
  __shared__ __align__(16) char smem[65536];

  const int tid  = threadIdx.x;
  const int wid  = tid >> 6;
  const int lane = tid & 63;
  const int hi   = lane >> 5;
  const int c    = lane & 31;

  // heavy-first decode: blocks 0..255 -> qt 15..8, blocks 256..511 -> qt 0..7
  const int i    = blockIdx.x;
  const int half = i >> 8;
  const int idx  = i & 255;
  const int b    = idx >> 3;
  const int q3   = idx & 7;
  const int qt   = half ? q3 : (15 - q3);
  const int qb   = qt * QBLK;
  const int nt   = 2 * qt + 2;

  const float* Qb = Qg + (size_t)b * SQL * DH;
  const float* Kb = Kg + (size_t)b * SQL * DH;
  const float* Vb = Vg + (size_t)b * SQL * DH;
  float* Ob = Og + (size_t)b * SQL * DH;

  // 1/sqrt(128) * log2(e): softmax in base 2
  const float qscale = 0.08838834764831845f * 1.4426950408889634f;

  // ---- Q fragments (B-operand of swapped QK^T, 32x32x16):
  // lane (hi,c) holds Q[q = qb+32*wid+c][d = 16*ds + 8*hi + j], j=0..7
  s16x8 qf[8];
  {
    const float* qr = Qb + (size_t)(qb + 32*wid + c) * DH + 8*hi;
    #pragma unroll
    for (int ds = 0; ds < 8; ++ds) {
      f32x4 a = *(const f32x4*)(qr + 16*ds);
      f32x4 d = *(const f32x4*)(qr + 16*ds + 4);
      u32x4 w;
      w[0] = pk2(a[0]*qscale, a[1]*qscale);
      w[1] = pk2(a[2]*qscale, a[3]*qscale);
      w[2] = pk2(d[0]*qscale, d[1]*qscale);
      w[3] = pk2(d[2]*qscale, d[3]*qscale);
      qf[ds] = __builtin_bit_cast(s16x8, w);
    }
  }

  f32x16 oacc[4];
  #pragma unroll
  for (int nb = 0; nb < 4; ++nb) oacc[nb] = (f32x16){0.f};
  float m_run = -1e30f, l_run = 0.f;

  const int qglob = qb + 32*wid + c;
  const int qhiw  = qb + 32*wid + 31;
  const int qlow  = qb + 32*wid;

  // staging maps
  const int kr  = tid >> 4;   // K row base 0..15 (+16*it)
  const int kc8 = tid & 15;   // K d-octet
  const int vkq = tid & 15;   // V k-quad
  const int vdq = tid >> 4;   // V d-quad base 0..15 (+16*dd)

  f32x4 kpre[8], vpre[8];
  {  // prologue: tile 0
    #pragma unroll
    for (int it = 0; it < 4; ++it) {
      const float* p = Kb + (size_t)(kr + 16*it) * DH + 8*kc8;
      kpre[2*it]   = *(const f32x4*)(p);
      kpre[2*it+1] = *(const f32x4*)(p + 4);
    }
    #pragma unroll
    for (int dd = 0; dd < 2; ++dd)
      #pragma unroll
      for (int j = 0; j < 4; ++j)
        vpre[4*dd + j] = *(const f32x4*)(Vb + (size_t)(4*vkq + j) * DH + 4*(vdq + 16*dd));
  }

  for (int t = 0; t < nt; ++t) {
    const int buf = t & 1;
    const int kb  = t * KBLK;
    char* Kl = smem + buf * 16384;
    char* Vl = smem + 32768 + buf * 16384;

    // ---- convert staged regs -> LDS[buf] (swizzled)
    #pragma unroll
    for (int it = 0; it < 4; ++it) {
      const int row = kr + 16*it;
      f32x4 a = kpre[2*it], d2 = kpre[2*it+1];
      u32x4 w;
      w[0] = pk2(a[0], a[1]);  w[1] = pk2(a[2], a[3]);
      w[2] = pk2(d2[0], d2[1]); w[3] = pk2(d2[2], d2[3]);
      *(u32x4*)(Kl + ((row*256 + 16*kc8) ^ ((row & 7) << 4))) = w;
    }
    #pragma unroll
    for (int dd = 0; dd < 2; ++dd)
      #pragma unroll
      for (int j2 = 0; j2 < 4; ++j2) {
        const int row = 4*(vdq + 16*dd) + j2;   // Vt row = d
        uint2 pkk = make_uint2(pk2(vpre[4*dd+0][j2], vpre[4*dd+1][j2]),
                               pk2(vpre[4*dd+2][j2], vpre[4*dd+3][j2]));
        *(uint2*)(Vl + ((row*128 + 8*vkq) ^ ((row & 7) << 4))) = pkk;
      }

    // ---- prefetch next tile (stays in flight across the barrier)
    if (t + 1 < nt) {
      const int kn = (t + 1) * KBLK;
      const float* ks = Kb + (size_t)kn * DH;
      #pragma unroll
      for (int it = 0; it < 4; ++it) {
        const float* p = ks + (size_t)(kr + 16*it) * DH + 8*kc8;
        kpre[2*it]   = *(const f32x4*)(p);
        kpre[2*it+1] = *(const f32x4*)(p + 4);
      }
      const float* vs = Vb + (size_t)kn * DH;
      #pragma unroll
      for (int dd = 0; dd < 2; ++dd)
        #pragma unroll
        for (int j = 0; j < 4; ++j)
          vpre[4*dd + j] = *(const f32x4*)(vs + (size_t)(4*vkq + j) * DH + 4*(vdq + 16*dd));
    }

    asm volatile("s_waitcnt lgkmcnt(0)" ::: "memory");
    __builtin_amdgcn_s_barrier();
    __builtin_amdgcn_sched_barrier(0);

    if (kb <= qhiw) {
      // ---- QK^T swapped: S^T[k][q], A = K from LDS, B = Q regs
      f32x16 sacc[2];
      sacc[0] = (f32x16){0.f};
      sacc[1] = (f32x16){0.f};
      __builtin_amdgcn_s_setprio(1);
      #pragma unroll
      for (int ds = 0; ds < 8; ++ds) {
        #pragma unroll
        for (int mb = 0; mb < 2; ++mb) {
          const int row = 32*mb + c;
          s16x8 kf = *(const s16x8*)(Kl + ((row*256 + 32*ds + 16*hi) ^ ((c & 7) << 4)));
          sacc[mb] = __builtin_amdgcn_mfma_f32_32x32x16_bf16(kf, qf[ds], sacc[mb], 0, 0, 0);
        }
      }
      __builtin_amdgcn_s_setprio(0);

      // ---- causal mask (diag-crossing tiles): lane holds S^T[k=kb+32mb+crow(r,hi)][q=c]
      if (kb + KBLK - 1 > qlow) {
        #pragma unroll
        for (int mb = 0; mb < 2; ++mb)
          #pragma unroll
          for (int r = 0; r < 16; ++r) {
            const int kk = kb + 32*mb + (r & 3) + 8*(r >> 2) + 4*hi;
            if (kk > qglob) sacc[mb][r] = -1e30f;
          }
      }

      // ---- row max (tree), q = c per lane; partner half at lane^32
      float mx[8];
      #pragma unroll
      for (int e = 0; e < 8; ++e)
        mx[e] = fmaxf(fmaxf(sacc[0][e], sacc[0][e+8]), fmaxf(sacc[1][e], sacc[1][e+8]));
      mx[0] = fmaxf(mx[0], mx[4]); mx[1] = fmaxf(mx[1], mx[5]);
      mx[2] = fmaxf(mx[2], mx[6]); mx[3] = fmaxf(mx[3], mx[7]);
      float tmax = fmaxf(fmaxf(mx[0], mx[1]), fmaxf(mx[2], mx[3]));
      tmax = fmaxf(tmax, __shfl_xor(tmax, 32));

      // ---- defer-max (T13): only rescale when max grew by > 8 (log2 units)
      if (!__all(tmax <= m_run + 8.0f)) {
        const float mnew  = fmaxf(m_run, tmax);
        const float alpha = exp2f(m_run - mnew);
        #pragma unroll
        for (int r = 0; r < 16; ++r) {
          float av = __shfl(alpha, (r & 3) + 8*(r >> 2) + 4*hi);
          #pragma unroll
          for (int nb = 0; nb < 4; ++nb) oacc[nb][r] *= av;
        }
        l_run *= alpha;
        m_run = mnew;
      }

      // ---- p = exp2(s - m), l-sum, pack bf16 pairs
      float lsum = 0.f;
      unsigned int u0[8], u1[8];
      {
        float p[16];
        #pragma unroll
        for (int r = 0; r < 16; ++r) p[r] = exp2f(sacc[0][r] - m_run);
        lsum += ((p[0]+p[1])+(p[2]+p[3])) + ((p[4]+p[5])+(p[6]+p[7]))
              + ((p[8]+p[9])+(p[10]+p[11])) + ((p[12]+p[13])+(p[14]+p[15]));
        #pragma unroll
        for (int w = 0; w < 8; ++w) u0[w] = cvtpk_bf16(p[2*w], p[2*w+1]);
      }
      {
        float p[16];
        #pragma unroll
        for (int r = 0; r < 16; ++r) p[r] = exp2f(sacc[1][r] - m_run);
        lsum += ((p[0]+p[1])+(p[2]+p[3])) + ((p[4]+p[5])+(p[6]+p[7]))
              + ((p[8]+p[9])+(p[10]+p[11])) + ((p[12]+p[13])+(p[14]+p[15]));
        #pragma unroll
        for (int w = 0; w < 8; ++w) u1[w] = cvtpk_bf16(p[2*w], p[2*w+1]);
      }
      lsum += __shfl_xor(lsum, 32);
      l_run += lsum;

      // ---- in-register P -> PV A-frags via permlane32_swap (T12)
      // After swap: first arg keeps its lo-half k-pair {base+0,1}/{+2,3} and gains
      // the partner's lo {base+8,9}/{+10,11}; second arg becomes {+4,5}|{+12,13} etc.
      PLSWAP(u0[0], u0[2]); PLSWAP(u0[1], u0[3]);
      PLSWAP(u0[4], u0[6]); PLSWAP(u0[5], u0[7]);
      PLSWAP(u1[0], u1[2]); PLSWAP(u1[1], u1[3]);
      PLSWAP(u1[4], u1[6]); PLSWAP(u1[5], u1[7]);
      s16x8 pa[4];
      { u32x4 w = {u0[0], u0[1], u0[2], u0[3]}; pa[0] = __builtin_bit_cast(s16x8, w); }
      { u32x4 w = {u0[4], u0[5], u0[6], u0[7]}; pa[1] = __builtin_bit_cast(s16x8, w); }
      { u32x4 w = {u1[0], u1[1], u1[2], u1[3]}; pa[2] = __builtin_bit_cast(s16x8, w); }
      { u32x4 w = {u1[4], u1[5], u1[6], u1[7]}; pa[3] = __builtin_bit_cast(s16x8, w); }

      // ---- PV: O[q][d] += P[q][k] Vt[d][k]^T  (A = P regs, B = V from LDS)
      __builtin_amdgcn_s_setprio(1);
      #pragma unroll
      for (int nb = 0; nb < 4; ++nb) {
        #pragma unroll
        for (int ks = 0; ks < 4; ++ks) {
          const int row = 32*nb + c;
          s16x8 vf = *(const s16x8*)(Vl + ((row*128 + 32*ks + 16*hi) ^ ((c & 7) << 4)));
          oacc[nb] = __builtin_amdgcn_mfma_f32_32x32x16_bf16(pa[ks], vf, oacc[nb], 0, 0, 0);
        }
      }
      __builtin_amdgcn_s_setprio(0);
    }
  }

  // ---- epilogue: O rows q = crow(r,hi), cols d = 32nb + c
  const float linv = 1.0f / l_run;
  float* Orow = Ob + (size_t)(qb + 32*wid) * DH;
  #pragma unroll
  for (int r = 0; r < 16; ++r) {
    const int q = (r & 3) + 8*(r >> 2) + 4*hi;
    float lv = __shfl(linv, q);
    #pragma unroll
    for (int nb = 0; nb < 4; ++nb)
      Orow[(size_t)q * DH + 32*nb + c] = oacc[nb][r] * lv;
  }
}

extern "C" void kernel_launch(void* const* d_in, const int* in_sizes, int n_in,
                              void* d_out, int out_size, void* d_ws, size_t ws_size,
                              hipStream_t stream) {
  const float* Q = (const float*)d_in[0];
  const float* K = (const float*)d_in[1];
  const float* V = (const float*)d_in[2];
  // d_in[3]: causal mask, deterministic (triu k=1) -> synthesized in-kernel
  float* O = (float*)d_out;
  dim3 grid(NB * (SQL / QBLK));
  dim3 block(256);
  attn_fwd<<<grid, block, 0, stream>>>(Q, K, V, O);
}

// Round 5
// 100.369 us; speedup vs baseline: 1.7875x; 1.7875x over previous
//
#include <hip/hip_runtime.h>
#include <hip/hip_bf16.h>

#define NB   32
#define SQL  2048
#define DH   128
#define QBLK 128
#define KBLK 64
#define NKT  (SQL / KBLK)      // 32 k-tiles per batch
#define TILEB 16384            // bytes per (64x128 bf16) tile image

typedef __attribute__((ext_vector_type(4))) float f32x4;
typedef __attribute__((ext_vector_type(8))) short s16x8;
typedef __attribute__((ext_vector_type(4))) unsigned int u32x4;

__device__ __forceinline__ unsigned int pk2(float lo, float hi) {
  unsigned short a = __builtin_bit_cast(unsigned short, __float2bfloat16(lo));
  unsigned short b = __builtin_bit_cast(unsigned short, __float2bfloat16(hi));
  return (unsigned int)a | ((unsigned int)b << 16);
}

#define AS1(p) ((const __attribute__((address_space(1))) void*)(p))
#define AS3(p) ((__attribute__((address_space(3))) void*)(p))

// ---------------- pass 1: K/V -> bf16 tiles in pre-swizzled LDS-image layout ----
// K image:  img[(r*256 + 2*d) ^ ((r&7)<<4)]  = bf16(K[r][d])   (r = k-row 0..63)
// Vt image: img[(d*128 + 2*k) ^ ((d&7)<<4)]  = bf16(V[k][d])   (d = 0..127, k = 0..63)
__global__ __launch_bounds__(256)
void prep_kv(const float* __restrict__ Kg, const float* __restrict__ Vg,
             char* __restrict__ wsK, char* __restrict__ wsV) {
  const int blk = blockIdx.x;          // b*32 + kt
  const int b   = blk >> 5;
  const int kt  = blk & 31;
  const int tid = threadIdx.x;
  const float* Ksrc = Kg + ((size_t)b * SQL + (size_t)kt * KBLK) * DH;
  const float* Vsrc = Vg + ((size_t)b * SQL + (size_t)kt * KBLK) * DH;
  char* Kdst = wsK + (size_t)blk * TILEB;
  char* Vdst = wsV + (size_t)blk * TILEB;

  {  // K: row-major bf16, swizzled
    const int q16 = tid & 15;          // 16B chunk (8 d-elems)
    const int r0  = tid >> 4;          // row 0..15
    #pragma unroll
    for (int it = 0; it < 4; ++it) {
      const int r = r0 + 16 * it;
      const float* src = Ksrc + (size_t)r * DH + 8 * q16;
      f32x4 a = *(const f32x4*)(src);
      f32x4 d = *(const f32x4*)(src + 4);
      u32x4 w;
      w[0] = pk2(a[0], a[1]); w[1] = pk2(a[2], a[3]);
      w[2] = pk2(d[0], d[1]); w[3] = pk2(d[2], d[3]);
      *(u32x4*)(Kdst + ((r * 256 + 16 * q16) ^ ((r & 7) << 4))) = w;
    }
  }
  {  // V: transposed Vt[d][k], swizzled (4x4 register transpose)
    const int kq = tid & 15;           // k0 = 4*kq
    const int dq = tid >> 4;           // d0 = 4*dq (+64 per it)
    #pragma unroll
    for (int it = 0; it < 2; ++it) {
      const int d0 = 4 * dq + 64 * it;
      f32x4 rv[4];
      #pragma unroll
      for (int j = 0; j < 4; ++j)
        rv[j] = *(const f32x4*)(Vsrc + (size_t)(4 * kq + j) * DH + d0);
      #pragma unroll
      for (int j2 = 0; j2 < 4; ++j2) {
        const int dd = d0 + j2;
        uint2 w = make_uint2(pk2(rv[0][j2], rv[1][j2]), pk2(rv[2][j2], rv[3][j2]));
        *(uint2*)(Vdst + ((dd * 128 + 8 * kq) ^ ((dd & 7) << 4))) = w;
      }
    }
  }
}

// ---------------- pass 2: flash attention, global_load_lds staging ----------------
__global__ __launch_bounds__(512, 4)
void attn_fwd(const float* __restrict__ Qg, const char* __restrict__ wsK,
              const char* __restrict__ wsV, float* __restrict__ Og) {
  // K dbuf 2x16KB @0, Vt dbuf 2x16KB @32768, P 8 waves x 2KB @65536. 80KB total.
  __shared__ __align__(16) char smem[81920];

  const int tid  = threadIdx.x;
  const int wid  = tid >> 6;
  const int lane = tid & 63;
  const int g    = lane >> 4;
  const int ln   = lane & 15;

  // heavy-first: blocks 0..255 -> qt 15..8, blocks 256..511 -> qt 0..7
  const int i    = blockIdx.x;
  const int half = i >> 8;
  const int idx  = i & 255;
  const int b    = idx >> 3;
  const int q3   = idx & 7;
  const int qt   = half ? q3 : (15 - q3);
  const int qb   = qt * QBLK;
  const int nt   = 2 * qt + 2;

  const float* Qb = Qg + (size_t)b * SQL * DH;
  float* Ob = Og + (size_t)b * SQL * DH;
  const char* Ktiles = wsK + (size_t)b * NKT * TILEB;
  const char* Vtiles = wsV + (size_t)b * NKT * TILEB;

  const float qscale = 0.08838834764831845f * 1.4426950408889634f;  // 1/sqrt(128)*log2e

  // ---- Q fragments (fp32 -> bf16, scaled); lane holds Q[qb+16wid+ln][8g+j+32c]
  s16x8 qf[4];
  {
    const float* qr = Qb + (size_t)(qb + 16 * wid + ln) * DH + 8 * g;
    #pragma unroll
    for (int c = 0; c < 4; ++c) {
      f32x4 a  = *(const f32x4*)(qr + 32 * c);
      f32x4 b4 = *(const f32x4*)(qr + 32 * c + 4);
      u32x4 w;
      w[0] = pk2(a[0] * qscale, a[1] * qscale);
      w[1] = pk2(a[2] * qscale, a[3] * qscale);
      w[2] = pk2(b4[0] * qscale, b4[1] * qscale);
      w[3] = pk2(b4[2] * qscale, b4[3] * qscale);
      qf[c] = __builtin_bit_cast(s16x8, w);
    }
  }

  f32x4 oacc[8];
  #pragma unroll
  for (int ot = 0; ot < 8; ++ot) oacc[ot] = (f32x4){0.f, 0.f, 0.f, 0.f};
  float m_run = -1e30f, l_run = 0.f;

  const int qglob = qb + 16 * wid + ln;
  const int qmax  = qb + 16 * wid + 15;

  // stage tile t into LDS buf (t&1): wave wid covers bytes [wid*2048, +2048)
  auto STAGE = [&](int t) {
    const char* ks = Ktiles + (size_t)t * TILEB + wid * 2048 + lane * 16;
    const char* vs = Vtiles + (size_t)t * TILEB + wid * 2048 + lane * 16;
    char* kl = smem + (t & 1) * 16384 + wid * 2048;
    char* vl = smem + 32768 + (t & 1) * 16384 + wid * 2048;
    __builtin_amdgcn_global_load_lds(AS1(ks),        AS3(kl),        16, 0, 0);
    __builtin_amdgcn_global_load_lds(AS1(ks + 1024), AS3(kl + 1024), 16, 0, 0);
    __builtin_amdgcn_global_load_lds(AS1(vs),        AS3(vl),        16, 0, 0);
    __builtin_amdgcn_global_load_lds(AS1(vs + 1024), AS3(vl + 1024), 16, 0, 0);
  };

  STAGE(0);
  STAGE(1);   // nt >= 2 always

  for (int t = 0; t < nt; ++t) {
    // counted vmcnt: tile t's 4 loads are the oldest; t+1's 4 stay in flight
    if (t == nt - 1) asm volatile("s_waitcnt vmcnt(0)" ::: "memory");
    else             asm volatile("s_waitcnt vmcnt(4)" ::: "memory");
    __builtin_amdgcn_s_barrier();
    __builtin_amdgcn_sched_barrier(0);

    const int kb = t * KBLK;
    const char* Kl = smem + (t & 1) * 16384;
    const char* Vl = smem + 32768 + (t & 1) * 16384;
    char* Pw = smem + 65536 + wid * 2048;

    if (kb <= qmax) {
      // ---- QK^T swapped: S^T[k][q], A = K (LDS), B = Q (regs)
      f32x4 sacc[4];
      #pragma unroll
      for (int m = 0; m < 4; ++m) sacc[m] = (f32x4){0.f, 0.f, 0.f, 0.f};
      __builtin_amdgcn_s_setprio(1);
      #pragma unroll
      for (int c = 0; c < 4; ++c) {
        #pragma unroll
        for (int m = 0; m < 4; ++m) {
          s16x8 kf = *(const s16x8*)(Kl + (((16 * m + ln) * 256 + 16 * g + 64 * c) ^ ((ln & 7) << 4)));
          sacc[m] = __builtin_amdgcn_mfma_f32_16x16x32_bf16(kf, qf[c], sacc[m], 0, 0, 0);
        }
      }
      __builtin_amdgcn_s_setprio(0);

      // ---- causal mask (diag-crossing tiles); lane holds S^T[k=kb+16m+4g+r][q=ln]
      if (kb + KBLK - 1 > qb + 16 * wid) {
        #pragma unroll
        for (int m = 0; m < 4; ++m)
          #pragma unroll
          for (int r = 0; r < 4; ++r) {
            const int kk = kb + 16 * m + 4 * g + r;
            if (kk > qglob) sacc[m][r] = -1e30f;
          }
      }

      // ---- online softmax (base-2); row q=ln spread over lanes {ln, ln^16, ln^32, ln^48}
      float tmax = sacc[0][0];
      #pragma unroll
      for (int m = 0; m < 4; ++m)
        #pragma unroll
        for (int r = 0; r < 4; ++r) tmax = fmaxf(tmax, sacc[m][r]);
      tmax = fmaxf(tmax, __shfl_xor(tmax, 16));
      tmax = fmaxf(tmax, __shfl_xor(tmax, 32));
      const float mnew  = fmaxf(m_run, tmax);
      const float alpha = exp2f(m_run - mnew);
      float lsum = 0.f;
      unsigned int pw[4][2];
      #pragma unroll
      for (int m = 0; m < 4; ++m) {
        float p0 = exp2f(sacc[m][0] - mnew);
        float p1 = exp2f(sacc[m][1] - mnew);
        float p2 = exp2f(sacc[m][2] - mnew);
        float p3 = exp2f(sacc[m][3] - mnew);
        lsum += (p0 + p1) + (p2 + p3);
        pw[m][0] = pk2(p0, p1);
        pw[m][1] = pk2(p2, p3);
      }
      lsum += __shfl_xor(lsum, 16);
      lsum += __shfl_xor(lsum, 32);
      l_run = l_run * alpha + lsum;
      m_run = mnew;

      // rescale O (rows q = 4g+r live at lane 4g+r within the 16-group)
      float ar[4];
      #pragma unroll
      for (int r = 0; r < 4; ++r) ar[r] = __shfl(alpha, 4 * g + r);
      #pragma unroll
      for (int ot = 0; ot < 8; ++ot)
        #pragma unroll
        for (int r = 0; r < 4; ++r) oacc[ot][r] *= ar[r];

      // ---- P[q=ln][k=16m+4g..+3] -> per-wave LDS (swizzled, wave-local)
      #pragma unroll
      for (int m = 0; m < 4; ++m)
        *(uint2*)(Pw + ((ln * 128 + 32 * m + 8 * g) ^ ((ln & 7) << 4))) =
            make_uint2(pw[m][0], pw[m][1]);

      // ---- PV: O[q][d] += P[q][k] * Vt[d][k]^T
      s16x8 pf[2];
      #pragma unroll
      for (int c2 = 0; c2 < 2; ++c2)
        pf[c2] = *(const s16x8*)(Pw + ((ln * 128 + 16 * g + 64 * c2) ^ ((ln & 7) << 4)));
      __builtin_amdgcn_s_setprio(1);
      #pragma unroll
      for (int ot = 0; ot < 8; ++ot) {
        #pragma unroll
        for (int c2 = 0; c2 < 2; ++c2) {
          s16x8 vf = *(const s16x8*)(Vl + (((16 * ot + ln) * 128 + 16 * g + 64 * c2) ^ ((ln & 7) << 4)));
          oacc[ot] = __builtin_amdgcn_mfma_f32_16x16x32_bf16(pf[c2], vf, oacc[ot], 0, 0, 0);
        }
      }
      __builtin_amdgcn_s_setprio(0);
    }

    __builtin_amdgcn_s_barrier();     // all waves done with buf (t&1)
    if (t + 2 < nt) STAGE(t + 2);     // overwrite it for tile t+2
  }

  // ---- epilogue
  const float linv = 1.0f / l_run;
  float lr[4];
  #pragma unroll
  for (int r = 0; r < 4; ++r) lr[r] = __shfl(linv, 4 * g + r);
  float* orow = Ob + (size_t)(qb + 16 * wid) * DH + ln;
  #pragma unroll
  for (int ot = 0; ot < 8; ++ot)
    #pragma unroll
    for (int r = 0; r < 4; ++r)
      orow[(size_t)(4 * g + r) * DH + 16 * ot] = oacc[ot][r] * lr[r];
}

extern "C" void kernel_launch(void* const* d_in, const int* in_sizes, int n_in,
                              void* d_out, int out_size, void* d_ws, size_t ws_size,
                              hipStream_t stream) {
  const float* Q = (const float*)d_in[0];
  const float* K = (const float*)d_in[1];
  const float* V = (const float*)d_in[2];
  // d_in[3]: causal mask, deterministic (triu k=1) -> synthesized in-kernel
  float* O = (float*)d_out;
  char* wsK = (char*)d_ws;                                   // 16 MB
  char* wsV = (char*)d_ws + (size_t)NB * NKT * TILEB;        // 16 MB

  prep_kv<<<dim3(NB * NKT), dim3(256), 0, stream>>>(K, V, wsK, wsV);
  attn_fwd<<<dim3(NB * (SQL / QBLK)), dim3(512), 0, stream>>>(Q, wsK, wsV, O);
}

// Round 6
// 89.423 us; speedup vs baseline: 2.0063x; 1.1224x over previous
//
#include <hip/hip_runtime.h>
#include <hip/hip_bf16.h>

#define NB   32
#define SQL  2048
#define DH   128
#define QBLK 128
#define KBLK 64
#define NKT  (SQL / KBLK)      // 32 k-tiles per batch
#define TILEB 16384            // bytes per (64x128 bf16) tile image

typedef __attribute__((ext_vector_type(4)))  float f32x4;
typedef __attribute__((ext_vector_type(16))) float f32x16;
typedef __attribute__((ext_vector_type(8)))  short s16x8;
typedef __attribute__((ext_vector_type(4)))  unsigned int u32x4;

__device__ __forceinline__ unsigned int cvtpk_bf16(float lo, float hi) {
  unsigned int r;
  asm("v_cvt_pk_bf16_f32 %0, %1, %2" : "=v"(r) : "v"(lo), "v"(hi));
  return r;
}
// x.hi32 = y.lo32 ; y.lo32 = x.hi32_old  (x keeps lo, y keeps hi)
#define PLSWAP(x, y) asm volatile("v_permlane32_swap_b32 %0, %1" : "+v"(x), "+v"(y))

__device__ __forceinline__ unsigned int pk2(float lo, float hi) {
  unsigned short a = __builtin_bit_cast(unsigned short, __float2bfloat16(lo));
  unsigned short b = __builtin_bit_cast(unsigned short, __float2bfloat16(hi));
  return (unsigned int)a | ((unsigned int)b << 16);
}

#define AS1(p) ((const __attribute__((address_space(1))) void*)(p))
#define AS3(p) ((__attribute__((address_space(3))) void*)(p))

// ---------------- pass 1: K/V -> bf16 tiles in pre-swizzled LDS-image layout ----
// K image:  img[(r*256 + 2*d) ^ ((r&7)<<4)]  = bf16(K[r][d])   (r = k-row 0..63)
// Vt image: img[(d*128 + 2*k) ^ ((d&7)<<4)]  = bf16(V[k][d])   (d = 0..127, k = 0..63)
__global__ __launch_bounds__(256)
void prep_kv(const float* __restrict__ Kg, const float* __restrict__ Vg,
             char* __restrict__ wsK, char* __restrict__ wsV) {
  const int blk = blockIdx.x;          // b*32 + kt
  const int b   = blk >> 5;
  const int kt  = blk & 31;
  const int tid = threadIdx.x;
  const float* Ksrc = Kg + ((size_t)b * SQL + (size_t)kt * KBLK) * DH;
  const float* Vsrc = Vg + ((size_t)b * SQL + (size_t)kt * KBLK) * DH;
  char* Kdst = wsK + (size_t)blk * TILEB;
  char* Vdst = wsV + (size_t)blk * TILEB;

  {  // K: row-major bf16, swizzled
    const int q16 = tid & 15;          // 16B chunk (8 d-elems)
    const int r0  = tid >> 4;          // row 0..15
    #pragma unroll
    for (int it = 0; it < 4; ++it) {
      const int r = r0 + 16 * it;
      const float* src = Ksrc + (size_t)r * DH + 8 * q16;
      f32x4 a = *(const f32x4*)(src);
      f32x4 d = *(const f32x4*)(src + 4);
      u32x4 w;
      w[0] = pk2(a[0], a[1]); w[1] = pk2(a[2], a[3]);
      w[2] = pk2(d[0], d[1]); w[3] = pk2(d[2], d[3]);
      *(u32x4*)(Kdst + ((r * 256 + 16 * q16) ^ ((r & 7) << 4))) = w;
    }
  }
  {  // V: transposed Vt[d][k], swizzled (4x4 register transpose)
    const int kq = tid & 15;           // k0 = 4*kq
    const int dq = tid >> 4;           // d0 = 4*dq (+64 per it)
    #pragma unroll
    for (int it = 0; it < 2; ++it) {
      const int d0 = 4 * dq + 64 * it;
      f32x4 rv[4];
      #pragma unroll
      for (int j = 0; j < 4; ++j)
        rv[j] = *(const f32x4*)(Vsrc + (size_t)(4 * kq + j) * DH + d0);
      #pragma unroll
      for (int j2 = 0; j2 < 4; ++j2) {
        const int dd = d0 + j2;
        uint2 w = make_uint2(pk2(rv[0][j2], rv[1][j2]), pk2(rv[2][j2], rv[3][j2]));
        *(uint2*)(Vdst + ((dd * 128 + 8 * kq) ^ ((dd & 7) << 4))) = w;
      }
    }
  }
}

// ---------------- pass 2: flash attention, 32 q-rows/wave, global_load_lds ------
__global__ __launch_bounds__(256, 2)
void attn_fwd(const float* __restrict__ Qg, const char* __restrict__ wsK,
              const char* __restrict__ wsV, float* __restrict__ Og) {
  // K dbuf: 2 x 16KB @0; Vt dbuf: 2 x 16KB @32768. No P buffer (in-register).
  __shared__ __align__(16) char smem[65536];

  const int tid  = threadIdx.x;
  const int wid  = tid >> 6;
  const int lane = tid & 63;
  const int hi   = lane >> 5;
  const int c    = lane & 31;

  // complementary-pair decode: blocks 2c/2c+1 AND i/i+256 are heavy/light
  // complements (nt sums to 34 either way) -> balanced per-CU load under
  // either consecutive or round-robin block->CU pairing.
  const int i   = blockIdx.x;
  const int p   = i & 1;
  const int q3  = (i >> 1) & 7;
  const int b   = (i >> 4) & 31;
  const int qtb = (b & 16) ? (15 - q3) : q3;
  const int qt  = p ? qtb : (15 - qtb);
  const int qb  = qt * QBLK;
  const int nt  = 2 * qt + 2;

  const float* Qb = Qg + (size_t)b * SQL * DH;
  float* Ob = Og + (size_t)b * SQL * DH;
  const char* Ktiles = wsK + (size_t)b * NKT * TILEB;
  const char* Vtiles = wsV + (size_t)b * NKT * TILEB;

  const float qscale = 0.08838834764831845f * 1.4426950408889634f;  // 1/sqrt(128)*log2e

  // ---- Q fragments (B-operand of swapped QK^T, 32x32x16):
  // lane (hi,c) holds Q[q = qb+32*wid+c][d = 16*ds + 8*hi + j], j=0..7
  s16x8 qf[8];
  {
    const float* qr = Qb + (size_t)(qb + 32*wid + c) * DH + 8*hi;
    #pragma unroll
    for (int ds = 0; ds < 8; ++ds) {
      f32x4 a = *(const f32x4*)(qr + 16*ds);
      f32x4 d = *(const f32x4*)(qr + 16*ds + 4);
      u32x4 w;
      w[0] = pk2(a[0]*qscale, a[1]*qscale);
      w[1] = pk2(a[2]*qscale, a[3]*qscale);
      w[2] = pk2(d[0]*qscale, d[1]*qscale);
      w[3] = pk2(d[2]*qscale, d[3]*qscale);
      qf[ds] = __builtin_bit_cast(s16x8, w);
    }
  }

  f32x16 oacc[4];
  #pragma unroll
  for (int nb = 0; nb < 4; ++nb) oacc[nb] = (f32x16){0.f};
  float m_run = -1e30f, l_run = 0.f;

  const int qglob = qb + 32*wid + c;
  const int qhiw  = qb + 32*wid + 31;
  const int qlow  = qb + 32*wid;

  // stage tile t into LDS buf (t&1): 8 x global_load_lds (4 K + 4 Vt), 16B/lane
  auto STAGE = [&](int t) {
    const char* ks = Ktiles + (size_t)t * TILEB + tid * 16;
    const char* vs = Vtiles + (size_t)t * TILEB + tid * 16;
    char* kl = smem + (t & 1) * 16384 + wid * 1024;
    char* vl = smem + 32768 + (t & 1) * 16384 + wid * 1024;
    #pragma unroll
    for (int j = 0; j < 4; ++j) {
      __builtin_amdgcn_global_load_lds(AS1(ks + j * 4096), AS3(kl + j * 4096), 16, 0, 0);
      __builtin_amdgcn_global_load_lds(AS1(vs + j * 4096), AS3(vl + j * 4096), 16, 0, 0);
    }
  };

  STAGE(0);
  STAGE(1);   // nt >= 2 always

  for (int t = 0; t < nt; ++t) {
    // counted vmcnt: tile t's 8 loads are oldest; tile t+1's 8 stay in flight
    if (t == nt - 1) asm volatile("s_waitcnt vmcnt(0)" ::: "memory");
    else             asm volatile("s_waitcnt vmcnt(8)" ::: "memory");
    __builtin_amdgcn_s_barrier();
    __builtin_amdgcn_sched_barrier(0);

    const int kb = t * KBLK;
    const char* Kl = smem + (t & 1) * 16384;
    const char* Vl = smem + 32768 + (t & 1) * 16384;

    if (kb <= qhiw) {
      // ---- QK^T swapped: S^T[k][q], A = K from LDS, B = Q regs
      f32x16 sacc[2];
      sacc[0] = (f32x16){0.f};
      sacc[1] = (f32x16){0.f};
      __builtin_amdgcn_s_setprio(1);
      #pragma unroll
      for (int ds = 0; ds < 8; ++ds) {
        #pragma unroll
        for (int mb = 0; mb < 2; ++mb) {
          const int row = 32*mb + c;
          s16x8 kf = *(const s16x8*)(Kl + ((row*256 + 32*ds + 16*hi) ^ ((c & 7) << 4)));
          sacc[mb] = __builtin_amdgcn_mfma_f32_32x32x16_bf16(kf, qf[ds], sacc[mb], 0, 0, 0);
        }
      }
      __builtin_amdgcn_s_setprio(0);

      // ---- causal mask (diag-crossing tiles): lane holds S^T[k=kb+32mb+crow(r,hi)][q=c]
      if (kb + KBLK - 1 > qlow) {
        #pragma unroll
        for (int mb = 0; mb < 2; ++mb)
          #pragma unroll
          for (int r = 0; r < 16; ++r) {
            const int kk = kb + 32*mb + (r & 3) + 8*(r >> 2) + 4*hi;
            if (kk > qglob) sacc[mb][r] = -1e30f;
          }
      }

      // ---- row max (tree), q = c per lane; partner half at lane^32
      float mx[8];
      #pragma unroll
      for (int e = 0; e < 8; ++e)
        mx[e] = fmaxf(fmaxf(sacc[0][e], sacc[0][e+8]), fmaxf(sacc[1][e], sacc[1][e+8]));
      mx[0] = fmaxf(mx[0], mx[4]); mx[1] = fmaxf(mx[1], mx[5]);
      mx[2] = fmaxf(mx[2], mx[6]); mx[3] = fmaxf(mx[3], mx[7]);
      float tmax = fmaxf(fmaxf(mx[0], mx[1]), fmaxf(mx[2], mx[3]));
      tmax = fmaxf(tmax, __shfl_xor(tmax, 32));

      // ---- defer-max (T13): only rescale when max grew by > 8 (log2 units)
      if (!__all(tmax <= m_run + 8.0f)) {
        const float mnew  = fmaxf(m_run, tmax);
        const float alpha = exp2f(m_run - mnew);
        #pragma unroll
        for (int r = 0; r < 16; ++r) {
          float av = __shfl(alpha, (r & 3) + 8*(r >> 2) + 4*hi);
          #pragma unroll
          for (int nb = 0; nb < 4; ++nb) oacc[nb][r] *= av;
        }
        l_run *= alpha;
        m_run = mnew;
      }

      // ---- p = exp2(s - m), l-sum, pack bf16 pairs
      float lsum = 0.f;
      unsigned int u0[8], u1[8];
      {
        float pz[16];
        #pragma unroll
        for (int r = 0; r < 16; ++r) pz[r] = exp2f(sacc[0][r] - m_run);
        lsum += ((pz[0]+pz[1])+(pz[2]+pz[3])) + ((pz[4]+pz[5])+(pz[6]+pz[7]))
              + ((pz[8]+pz[9])+(pz[10]+pz[11])) + ((pz[12]+pz[13])+(pz[14]+pz[15]));
        #pragma unroll
        for (int w = 0; w < 8; ++w) u0[w] = cvtpk_bf16(pz[2*w], pz[2*w+1]);
      }
      {
        float pz[16];
        #pragma unroll
        for (int r = 0; r < 16; ++r) pz[r] = exp2f(sacc[1][r] - m_run);
        lsum += ((pz[0]+pz[1])+(pz[2]+pz[3])) + ((pz[4]+pz[5])+(pz[6]+pz[7]))
              + ((pz[8]+pz[9])+(pz[10]+pz[11])) + ((pz[12]+pz[13])+(pz[14]+pz[15]));
        #pragma unroll
        for (int w = 0; w < 8; ++w) u1[w] = cvtpk_bf16(pz[2*w], pz[2*w+1]);
      }
      lsum += __shfl_xor(lsum, 32);
      l_run += lsum;

      // ---- in-register P -> PV A-frags via permlane32_swap (T12, HW-verified R4)
      PLSWAP(u0[0], u0[2]); PLSWAP(u0[1], u0[3]);
      PLSWAP(u0[4], u0[6]); PLSWAP(u0[5], u0[7]);
      PLSWAP(u1[0], u1[2]); PLSWAP(u1[1], u1[3]);
      PLSWAP(u1[4], u1[6]); PLSWAP(u1[5], u1[7]);
      s16x8 pa[4];
      { u32x4 w = {u0[0], u0[1], u0[2], u0[3]}; pa[0] = __builtin_bit_cast(s16x8, w); }
      { u32x4 w = {u0[4], u0[5], u0[6], u0[7]}; pa[1] = __builtin_bit_cast(s16x8, w); }
      { u32x4 w = {u1[0], u1[1], u1[2], u1[3]}; pa[2] = __builtin_bit_cast(s16x8, w); }
      { u32x4 w = {u1[4], u1[5], u1[6], u1[7]}; pa[3] = __builtin_bit_cast(s16x8, w); }

      // ---- PV: O[q][d] += P[q][k] Vt[d][k]^T  (A = P regs, B = V from LDS)
      __builtin_amdgcn_s_setprio(1);
      #pragma unroll
      for (int nb = 0; nb < 4; ++nb) {
        #pragma unroll
        for (int ks = 0; ks < 4; ++ks) {
          const int row = 32*nb + c;
          s16x8 vf = *(const s16x8*)(Vl + ((row*128 + 32*ks + 16*hi) ^ ((c & 7) << 4)));
          oacc[nb] = __builtin_amdgcn_mfma_f32_32x32x16_bf16(pa[ks], vf, oacc[nb], 0, 0, 0);
        }
      }
      __builtin_amdgcn_s_setprio(0);
    }

    __builtin_amdgcn_s_barrier();     // all waves done reading buf (t&1)
    if (t + 2 < nt) STAGE(t + 2);     // refill it for tile t+2
  }

  // ---- epilogue: O rows q = crow(r,hi), cols d = 32nb + c
  const float linv = 1.0f / l_run;
  float* Orow = Ob + (size_t)(qb + 32*wid) * DH;
  #pragma unroll
  for (int r = 0; r < 16; ++r) {
    const int q = (r & 3) + 8*(r >> 2) + 4*hi;
    float lv = __shfl(linv, q);
    #pragma unroll
    for (int nb = 0; nb < 4; ++nb)
      Orow[(size_t)q * DH + 32*nb + c] = oacc[nb][r] * lv;
  }
}

extern "C" void kernel_launch(void* const* d_in, const int* in_sizes, int n_in,
                              void* d_out, int out_size, void* d_ws, size_t ws_size,
                              hipStream_t stream) {
  const float* Q = (const float*)d_in[0];
  const float* K = (const float*)d_in[1];
  const float* V = (const float*)d_in[2];
  // d_in[3]: causal mask, deterministic (triu k=1) -> synthesized in-kernel
  float* O = (float*)d_out;
  char* wsK = (char*)d_ws;                                   // 16 MB
  char* wsV = (char*)d_ws + (size_t)NB * NKT * TILEB;        // 16 MB

  prep_kv<<<dim3(NB * NKT), dim3(256), 0, stream>>>(K, V, wsK, wsV);
  attn_fwd<<<dim3(NB * (SQL / QBLK)), dim3(256), 0, stream>>>(Q, wsK, wsV, O);
}